// Round 1
// baseline (121.680 us; speedup 1.0000x reference)
//
#include <hip/hip_runtime.h>

// YOLOX head decode: (N, A*85, H, W) -> (N, A*H*W, 85) with sigmoid on
// obj/cls and box decode on channels 0..3. Pure streaming transpose:
// coalesced float4 reads per channel-plane -> LDS [pos][85] -> coalesced
// float4 writes of the contiguous output region.

#define NATT 85
#define TP 64              // positions per block
#define TOTAL_ROWS 25200

__device__ __forceinline__ float sigmf(float v) {
    return 1.0f / (1.0f + __expf(-v));
}

template <int LVL>
__global__ __launch_bounds__(256) void yolox_kernel(const float* __restrict__ in,
                                                    float* __restrict__ out) {
    constexpr int   H  = (LVL == 0) ? 20 : (LVL == 1) ? 40 : 80;
    constexpr int   W  = H;
    constexpr int   HW = H * W;
    constexpr float S  = (LVL == 0) ? 32.f : (LVL == 1) ? 16.f : 8.f;
    constexpr int   OUT_BASE = (LVL == 0) ? 0 : (LVL == 1) ? 1200 : 6000;

    __shared__ float lds[TP * NATT];   // [pos][attrib], 21760 B

    const int tid   = threadIdx.x;     // 256 threads = 4 waves
    const int chunk = blockIdx.x;      // position chunk
    const int a     = blockIdx.y;      // anchor 0..2
    const int n     = blockIdx.z;      // batch

    const int pos0  = chunk * TP;
    const int valid = (HW - pos0 < TP) ? (HW - pos0) : TP;  // 64, or 16 (lvl0 tail)

    // input plane base for (n, anchor a, k=0) at this position chunk
    const float* inp = in + ((size_t)n * 255 + (size_t)a * NATT) * HW + pos0;

    // ---- load phase: 16 lanes per plane, float4 along positions ----
    const int m = tid & 15;        // which float4 within the 64-pos chunk
    const int p = m * 4;           // position offset of this vec
    for (int kk = tid >> 4; kk < NATT; kk += 16) {
        if (p < valid) {           // valid is always a multiple of 4
            float4 v = *reinterpret_cast<const float4*>(inp + (size_t)kk * HW + p);
            if (kk >= 4) {
                v.x = sigmf(v.x); v.y = sigmf(v.y);
                v.z = sigmf(v.z); v.w = sigmf(v.w);
            }
            lds[(p + 0) * NATT + kk] = v.x;
            lds[(p + 1) * NATT + kk] = v.y;
            lds[(p + 2) * NATT + kk] = v.z;
            lds[(p + 3) * NATT + kk] = v.w;
        }
    }
    __syncthreads();

    // ---- fix-up phase: decode boxes in place (one lane per position) ----
    if (tid < TP && tid < valid) {
        const int gp = pos0 + tid;
        const int y  = gp / W;
        const int x  = gp - y * W;
        // anchor base sizes, selected by runtime a via cndmask (no local array)
        const float wa = (a == 0) ? ((LVL == 0) ? 116.f : (LVL == 1) ? 30.f : 10.f)
                       : (a == 1) ? ((LVL == 0) ? 156.f : (LVL == 1) ? 62.f : 16.f)
                                  : ((LVL == 0) ? 373.f : (LVL == 1) ? 59.f : 33.f);
        const float ha = (a == 0) ? ((LVL == 0) ?  90.f : (LVL == 1) ? 61.f : 13.f)
                       : (a == 1) ? ((LVL == 0) ? 198.f : (LVL == 1) ? 45.f : 30.f)
                                  : ((LVL == 0) ? 326.f : (LVL == 1) ? 119.f : 23.f);
        const float p0 = lds[tid * NATT + 0];
        const float p1 = lds[tid * NATT + 1];
        const float p2 = lds[tid * NATT + 2];
        const float p3 = lds[tid * NATT + 3];
        // (p0-0.5)*S + (x+0.5)*S == (p0+x)*S
        const float xc = (p0 + (float)x) * S;
        const float yc = (p1 + (float)y) * S;
        const float w  = __expf(p2) * wa;
        const float h  = __expf(p3) * ha;
        lds[tid * NATT + 0] = xc - 0.5f * w;
        lds[tid * NATT + 1] = yc - 0.5f * h;
        lds[tid * NATT + 2] = xc + 0.5f * w;
        lds[tid * NATT + 3] = yc + 0.5f * h;
    }
    __syncthreads();

    // ---- write phase: output region is valid*85 contiguous floats ----
    const size_t row0 = (size_t)n * TOTAL_ROWS + OUT_BASE + (size_t)a * HW + pos0;
    float* op = out + row0 * NATT;
    const int nfl = valid * NATT;          // 5440 or 1360, both divisible by 4
    for (int i = tid * 4; i + 3 < nfl; i += 1024) {
        *reinterpret_cast<float4*>(op + i) =
            *reinterpret_cast<const float4*>(lds + i);
    }
}

extern "C" void kernel_launch(void* const* d_in, const int* in_sizes, int n_in,
                              void* d_out, int out_size, void* d_ws, size_t ws_size,
                              hipStream_t stream) {
    const float* in0 = (const float*)d_in[0];  // (32,255,20,20)
    const float* in1 = (const float*)d_in[1];  // (32,255,40,40)
    const float* in2 = (const float*)d_in[2];  // (32,255,80,80)
    float* out = (float*)d_out;                // (32,25200,85)

    dim3 block(256);
    // chunks = ceil(HW/64): 400->7, 1600->25, 6400->100
    yolox_kernel<0><<<dim3(7,   3, 32), block, 0, stream>>>(in0, out);
    yolox_kernel<1><<<dim3(25,  3, 32), block, 0, stream>>>(in1, out);
    yolox_kernel<2><<<dim3(100, 3, 32), block, 0, stream>>>(in2, out);
}

// Round 2
// 98.053 us; speedup vs baseline: 1.2410x; 1.2410x over previous
//
#include <hip/hip_runtime.h>

// YOLOX head decode, fused single-launch version.
// (N, A*85, H, W) -> (N, A*H*W, 85) with sigmoid on obj/cls and box decode
// on channels 0..3. Streaming transpose: coalesced float4 reads per
// channel-plane -> LDS [pos][85] -> coalesced float4 writes of the
// contiguous output region. All three pyramid levels in ONE launch
// (biggest level first) to avoid inter-kernel drain/tail. Nontemporal
// loads/stores: every byte is touch-once, skip L2 fill.

typedef float v4f __attribute__((ext_vector_type(4)));

#define NATT 85
#define TP 64              // positions per block
#define TOTAL_ROWS 25200

__device__ __forceinline__ float sigmf(float v) {
    return 1.0f / (1.0f + __expf(-v));
}

template <int LVL>
__device__ __forceinline__ void process(const float* __restrict__ in,
                                        float* __restrict__ out,
                                        int id, float* lds) {
    constexpr int   H  = (LVL == 0) ? 20 : (LVL == 1) ? 40 : 80;
    constexpr int   W  = H;
    constexpr int   HW = H * W;
    constexpr float S  = (LVL == 0) ? 32.f : (LVL == 1) ? 16.f : 8.f;
    constexpr int   OUT_BASE = (LVL == 0) ? 0 : (LVL == 1) ? 1200 : 6000;
    constexpr int   C  = (HW + TP - 1) / TP;   // chunks per (n,a): 7 / 25 / 100

    const int tid   = threadIdx.x;     // 256 threads = 4 waves
    const int chunk = id % C;
    const int ta    = id / C;
    const int a     = ta % 3;          // anchor
    const int n     = ta / 3;          // batch

    const int pos0  = chunk * TP;
    const int valid = (HW - pos0 < TP) ? (HW - pos0) : TP;  // 64, or 16 (lvl0 tail)

    // input plane base for (n, anchor a, k=0) at this position chunk
    const float* inp = in + ((size_t)n * 255 + (size_t)a * NATT) * HW + pos0;

    // ---- load phase: 16 lanes per plane, float4 along positions ----
    const int m = tid & 15;        // which float4 within the 64-pos chunk
    const int p = m * 4;           // position offset of this vec
    for (int kk = tid >> 4; kk < NATT; kk += 16) {
        if (p < valid) {           // valid is always a multiple of 4
            v4f v = __builtin_nontemporal_load(
                reinterpret_cast<const v4f*>(inp + (size_t)kk * HW + p));
            if (kk >= 4) {
                v.x = sigmf(v.x); v.y = sigmf(v.y);
                v.z = sigmf(v.z); v.w = sigmf(v.w);
            }
            lds[(p + 0) * NATT + kk] = v.x;
            lds[(p + 1) * NATT + kk] = v.y;
            lds[(p + 2) * NATT + kk] = v.z;
            lds[(p + 3) * NATT + kk] = v.w;
        }
    }
    __syncthreads();

    // ---- fix-up phase: decode boxes in place (one lane per position) ----
    if (tid < TP && tid < valid) {
        const int gp = pos0 + tid;
        const int y  = gp / W;
        const int x  = gp - y * W;
        const float wa = (a == 0) ? ((LVL == 0) ? 116.f : (LVL == 1) ? 30.f : 10.f)
                       : (a == 1) ? ((LVL == 0) ? 156.f : (LVL == 1) ? 62.f : 16.f)
                                  : ((LVL == 0) ? 373.f : (LVL == 1) ? 59.f : 33.f);
        const float ha = (a == 0) ? ((LVL == 0) ?  90.f : (LVL == 1) ? 61.f : 13.f)
                       : (a == 1) ? ((LVL == 0) ? 198.f : (LVL == 1) ? 45.f : 30.f)
                                  : ((LVL == 0) ? 326.f : (LVL == 1) ? 119.f : 23.f);
        const float p0 = lds[tid * NATT + 0];
        const float p1 = lds[tid * NATT + 1];
        const float p2 = lds[tid * NATT + 2];
        const float p3 = lds[tid * NATT + 3];
        // (p0-0.5)*S + (x+0.5)*S == (p0+x)*S
        const float xc = (p0 + (float)x) * S;
        const float yc = (p1 + (float)y) * S;
        const float w  = __expf(p2) * wa;
        const float h  = __expf(p3) * ha;
        lds[tid * NATT + 0] = xc - 0.5f * w;
        lds[tid * NATT + 1] = yc - 0.5f * h;
        lds[tid * NATT + 2] = xc + 0.5f * w;
        lds[tid * NATT + 3] = yc + 0.5f * h;
    }
    __syncthreads();

    // ---- write phase: output region is valid*85 contiguous floats ----
    const size_t row0 = (size_t)n * TOTAL_ROWS + OUT_BASE + (size_t)a * HW + pos0;
    float* op = out + row0 * NATT;
    const int nfl = valid * NATT;          // 5440 or 1360, both divisible by 4
    for (int i = tid * 4; i + 3 < nfl; i += 1024) {
        __builtin_nontemporal_store(*reinterpret_cast<const v4f*>(lds + i),
                                    reinterpret_cast<v4f*>(op + i));
    }
}

// Block counts: lvl2 = 100*3*32 = 9600, lvl1 = 25*3*32 = 2400,
// lvl0 = 7*3*32 = 672. Total 12672. Biggest level first.
__global__ __launch_bounds__(256) void yolox_fused(const float* __restrict__ in0,
                                                   const float* __restrict__ in1,
                                                   const float* __restrict__ in2,
                                                   float* __restrict__ out) {
    __shared__ float lds[TP * NATT];   // 21760 B, shared by all paths
    const int bid = blockIdx.x;
    if (bid < 9600) {
        process<2>(in2, out, bid, lds);
    } else if (bid < 12000) {
        process<1>(in1, out, bid - 9600, lds);
    } else {
        process<0>(in0, out, bid - 12000, lds);
    }
}

extern "C" void kernel_launch(void* const* d_in, const int* in_sizes, int n_in,
                              void* d_out, int out_size, void* d_ws, size_t ws_size,
                              hipStream_t stream) {
    const float* in0 = (const float*)d_in[0];  // (32,255,20,20)
    const float* in1 = (const float*)d_in[1];  // (32,255,40,40)
    const float* in2 = (const float*)d_in[2];  // (32,255,80,80)
    float* out = (float*)d_out;                // (32,25200,85)

    yolox_fused<<<dim3(12672), dim3(256), 0, stream>>>(in0, in1, in2, out);
}